// Round 10
// baseline (144.054 us; speedup 1.0000x reference)
//
#include <hip/hip_runtime.h>
#include <math.h>

#define KSZ 5
#define TSX 16                // tile width (MFMA N = 16 pixels)
#define TSY 64                // tile height (each wave: 16 rows, 2 streams of 8)
#define HALO 3
#define FWX 22                // staged cols = TSX + 6
#define FH  70                // staged rows = TSY + 6
#define SCH 66                // sc rows = TSY + 2
#define PITCH 23              // uniform pitch for sf planes AND sc plane
#define SF_C (FH*PITCH)       // 1610 floats per flow channel
#define SC_BASE (2*SF_C)
#define SMF_TOT (SC_BASE + SCH*PITCH)

typedef __attribute__((ext_vector_type(8))) short short8_t;  // 8 bf16
typedef __attribute__((ext_vector_type(4))) float float4_t;
typedef __attribute__((ext_vector_type(2))) unsigned int uint2_t;

static __device__ __forceinline__ unsigned short f2bf(float f) {
    union { float f; unsigned int u; } v; v.f = f;
    return (unsigned short)((v.u + 0x7FFFu + ((v.u >> 16) & 1u)) >> 16);  // RNE
}
// truncating bf16 pack: low16 = hi16(a), high16 = hi16(b) — ONE v_perm_b32
static __device__ __forceinline__ unsigned int pk2t(float a, float b) {
    union { float f; unsigned int u; } ua, ub; ua.f = a; ub.f = b;
    return __builtin_amdgcn_perm(ub.u, ua.u, 0x07060302u);
}
static __device__ __forceinline__ float bflo(unsigned int u) {
    union { unsigned int u; float f; } v; v.u = u << 16; return v.f;
}
static __device__ __forceinline__ float bfhi(unsigned int u) {
    union { unsigned int u; float f; } v; v.u = u & 0xffff0000u; return v.f;
}

// GEMM2 output slot n -> (c, sel, idx); j = sel*15 + idx; valid: sel?idx<10:idx<15
static __device__ __forceinline__ void slot_decode(int n, int& c, int& sel, int& idx, bool& valid) {
    int g4c = (n >> 2) & 3;
    c = g4c >> 1; sel = g4c & 1;
    idx = ((n >> 4) << 2) + (n & 3);
    valid = sel ? (idx < 10) : (idx < 15);
}

// GEMM1 K-permutation: k-slot s -> original guidance k (c*9 + ky*3 + kx), -1 = zero
static __device__ __forceinline__ int kperm(int s) {
    int sg = s >> 3, sj = s & 7;
    if (sg < 3) return sg*9 + sj;     // plane sg, taps 0..7
    if (sj == 1) return 8;            // c0 tap 8
    if (sj == 2) return 17;           // c1 tap 8
    if (sj == 4) return 26;           // cons tap 8
    return -1;
}

// GEMM2 K-permutation: k-slot s -> h channel the owning lane already holds.
static __device__ __forceinline__ int kperm2(int s) {
    int g = s >> 3, j = s & 7;
    return (j < 4) ? (g*4 + j) : (16 + g*4 + (j - 4));
}

// ---- one-block pack kernel: weights/biases -> MFMA-fragment order in ws ----
__global__ __launch_bounds__(256)
void pack_kernel(const float* __restrict__ w1, const float* __restrict__ b1,
                 const float* __restrict__ w2, const float* __restrict__ b2,
                 unsigned short* __restrict__ wp, float* __restrict__ bp)
{
    const int tid = threadIdx.x;
    for (int i = tid; i < 6*64*8; i += 256) {
        int f = i >> 9, l = (i >> 3) & 63, j = i & 7;
        int m = l & 15, s = ((l >> 4) << 3) + j;
        float v;
        if (f < 2) {
            int k = kperm(s);
            v = (k >= 0) ? w1[(f*16 + m)*27 + k] : 0.f;
        } else {
            int n = (f - 2)*16 + m;
            int c, sel, idx; bool valid;
            slot_decode(n, c, sel, idx, valid);
            v = valid ? w2[(c*25 + sel*15 + idx)*32 + kperm2(s)] : 0.f;
        }
        wp[i] = f2bf(v);
    }
    for (int i = tid; i < 6*64*4; i += 256) {
        int f = i >> 8, l = (i >> 2) & 63, r = i & 3, g4 = l >> 4;
        float v;
        if (f < 2) v = b1[f*16 + g4*4 + r];
        else {
            int n = (f - 2)*16 + g4*4 + r;
            int c, sel, idx; bool valid;
            slot_decode(n, c, sel, idx, valid);
            v = valid ? b2[c*25 + sel*15 + idx] : 0.f;
        }
        bp[i] = v;
    }
}

__global__ __launch_bounds__(256, 5)   // LDS ~29 KB -> 5 blocks/CU
void refine_kernel(const float* __restrict__ flow,
                   const unsigned short* __restrict__ wp,
                   const float* __restrict__ bp,
                   float* __restrict__ out, int H, int W)
{
    __shared__ float smf[SMF_TOT];                 // sf[2][70][23] | sc[66][23]
    __shared__ __align__(8) uint2_t rs[FH*18];     // bf16-packed {sA|qA, sB|qB}

    const int tid = threadIdx.x;
    const int x0 = blockIdx.x * TSX;
    const int y0 = blockIdx.y * TSY;
    const int b  = blockIdx.z;

    const int lane = tid & 63;
    const int wave = tid >> 6;
    const int col  = lane & 15;
    const int g4   = lane >> 4;

    // ---- fragment loads from pre-packed ws ----
    short8_t w1A[2], w2A[4];
    float4_t cb1[2], cb2[4];
    #pragma unroll
    for (int nt = 0; nt < 2; ++nt) {
        w1A[nt] = *(const short8_t*)&wp[(nt*64 + lane)*8];
        cb1[nt] = *(const float4_t*)&bp[(nt*64 + lane)*4];
    }
    #pragma unroll
    for (int nt = 0; nt < 4; ++nt) {
        w2A[nt] = *(const short8_t*)&wp[((2+nt)*64 + lane)*8];
        cb2[nt] = *(const float4_t*)&bp[((2+nt)*64 + lane)*4];
    }

    // ---- phase 0: stage flow tile + halo ----
    {
        const float* srcb = flow + (size_t)(b*2) * H * W;
        if (x0 >= 4 && x0 + TSX + 4 <= W && y0 >= HALO && y0 + TSY + HALO <= H) {
            // interior: aligned float2 loads of 24 columns starting at x0-4
            const float* s = srcb + (size_t)(y0 - HALO) * W + (x0 - 4);
            for (int i = tid; i < 2*FH*12; i += 256) {
                int c = 0, r = i;
                if (r >= FH*12) { c = 1; r -= FH*12; }
                int ly = r / 12, lx2 = r - ly*12;
                float2 v = *(const float2*)(s + (size_t)c*H*W + (size_t)ly*W + 2*lx2);
                int dst = c*SF_C + ly*PITCH + 2*lx2 - 1;  // cols -1..22 -> -1 dropped
                if (dst >= 0) smf[dst] = v.x;
                smf[dst + 1] = v.y;
            }
        } else {
            for (int i = tid; i < 2*FH*FWX; i += 256) {
                int c = 0, r = i;
                if (r >= FH*FWX) { c = 1; r -= FH*FWX; }
                int ly = r / FWX, lx = r - ly*FWX;
                int gy = y0 - HALO + ly, gx = x0 - HALO + lx;
                float v = 0.f;
                if (gy >= 0 && gy < H && gx >= 0 && gx < W)
                    v = srcb[(size_t)c*H*W + (size_t)gy*W + gx];
                smf[c*SF_C + ly*PITCH + lx] = v;
            }
        }
    }
    __syncthreads();

    // ---- phase 1a: horizontal 5-tap sums (s, sum v^2), 2 adjacent outputs ----
    for (int i = tid; i < FH*9; i += 256) {        // 630 units
        int y = i / 9, xp = (i - y*9) * 2;
        const float* r0 = &smf[y*PITCH + xp];
        const float* r1 = &smf[SF_C + y*PITCH + xp];
        float a0=r0[0], a1=r0[1], a2=r0[2], a3=r0[3], a4=r0[4], a5=r0[5];
        float c0=r1[0], c1=r1[1], c2=r1[2], c3=r1[3], c4=r1[4], c5=r1[5];
        float sA = ((a0+a1)+(a2+a3))+a4;
        float qA = fmaf(a4,a4, fmaf(a3,a3, fmaf(a2,a2, fmaf(a1,a1, a0*a0))));
        float sB = ((c0+c1)+(c2+c3))+c4;
        float qB = fmaf(c4,c4, fmaf(c3,c3, fmaf(c2,c2, fmaf(c1,c1, c0*c0))));
        float sA1 = sA + a5 - a0;
        float qA1 = fmaf(-a0, a0, fmaf(a5, a5, qA));
        float sB1 = sB + c5 - c0;
        float qB1 = fmaf(-c0, c0, fmaf(c5, c5, qB));
        rs[y*18 + xp]     = (uint2_t){pk2t(sA,  qA ), pk2t(sB,  qB )};
        rs[y*18 + xp + 1] = (uint2_t){pk2t(sA1, qA1), pk2t(sB1, qB1)};
    }
    __syncthreads();

    // ---- phase 1b: vertical 5-row sums, 2 vertically-adjacent outputs/thread ----
    for (int i = tid; i < (SCH/2)*18; i += 256) {  // 594 units
        int u = i / 18, px = i - u*18;
        int py0 = u*2;
        int gx = x0 - 1 + px;
        int gy0 = y0 - 1 + py0;
        const uint2_t* rp = rs + py0*18 + px;
        float4_t f[6];
        #pragma unroll
        for (int k = 0; k < 6; ++k) {
            uint2_t uu = rp[k*18];
            f[k] = (float4_t){bflo(uu.x), bfhi(uu.x), bflo(uu.y), bfhi(uu.y)};
        }
        float4_t mid  = (f[1] + f[2]) + (f[3] + f[4]);
        float4_t acc0 = mid + f[0];
        float4_t acc1 = mid + f[5];
        float cons0 = 0.f, cons1 = 0.f;
        bool okx = (gx >= 0) && (gx < W);
        if (okx && gy0 >= 0 && gy0 < H) {
            float v0 = (acc0.y - acc0.x*acc0.x*(1.f/25.f)) * (1.f/24.f);
            float v1 = (acc0.w - acc0.z*acc0.z*(1.f/25.f)) * (1.f/24.f);
            cons0 = __expf(-sqrtf(v0*v0 + v1*v1));
        }
        if (okx && gy0+1 >= 0 && gy0+1 < H) {
            float v0 = (acc1.y - acc1.x*acc1.x*(1.f/25.f)) * (1.f/24.f);
            float v1 = (acc1.w - acc1.z*acc1.z*(1.f/25.f)) * (1.f/24.f);
            cons1 = __expf(-sqrtf(v0*v0 + v1*v1));
        }
        smf[SC_BASE + py0*PITCH + px]       = cons0;
        smf[SC_BASE + (py0+1)*PITCH + px]   = cons1;
    }
    __syncthreads();

    // ---- main: two independent row-streams per wave (ILP) ----
    const int sel = g4 & 1, pc = g4 >> 1;
    const int tyA = wave*16, tyB = wave*16 + 8;

    // guidance bases per stream (uniform immediates {0,1},{2,23},{24,25},{46,47})
    int gA0, gA1, gA2, gA3, gB0, gB1, gB2, gB3;
    {
        int p0 = 0*SF_C + 2*PITCH + (col + 2);
        int p1 = 1*SF_C + 2*PITCH + (col + 2);
        int p2 = SC_BASE + col;
        int q0, q1, q2, q3;
        if (g4 == 0)      { q0 = q1 = q2 = q3 = p0; }
        else if (g4 == 1) { q0 = q1 = q2 = q3 = p1; }
        else if (g4 == 2) { q0 = q1 = q2 = q3 = p2; }
        else { q0 = p0 + 47; q1 = p1 + 46; q2 = p2 + 24; q3 = p0; }
        gA0 = q0 + tyA*PITCH; gA1 = q1 + tyA*PITCH; gA2 = q2 + tyA*PITCH; gA3 = q3 + tyA*PITCH;
        gB0 = q0 + tyB*PITCH; gB1 = q1 + tyB*PITCH; gB2 = q2 + tyB*PITCH; gB3 = q3 + tyB*PITCH;
    }

    // patch pipelines per stream
    const int pbase = pc*SF_C + sel*(3*PITCH) + PITCH + 1 + col;
    int pbA = pbase + tyA*PITCH, pbB = pbase + tyB*PITCH;
    float pvA[15], pvB[15];
    #pragma unroll
    for (int i = 0; i < 15; ++i) pvA[i] = smf[pbA + (i/5)*PITCH + (i%5)];
    #pragma unroll
    for (int i = 0; i < 15; ++i) pvB[i] = smf[pbB + (i/5)*PITCH + (i%5)];

    #pragma unroll
    for (int mt = 0; mt < 8; ++mt) {
        // ---------- stream A ----------
        float sA;
        {
            float ga = smf[gA0 + 0],  gb_ = smf[gA0 + 1];
            float gc = smf[gA1 + 2],  gd  = smf[gA1 + 23];
            float ge = smf[gA2 + 24], gf  = smf[gA2 + 25];
            float gg = smf[gA3 + 46], gh  = smf[gA3 + 47];
            union { unsigned int u[4]; short8_t s; } gu;
            gu.u[0] = pk2t(ga, gb_); gu.u[1] = pk2t(gc, gd);
            gu.u[2] = pk2t(ge, gf);  gu.u[3] = pk2t(gg, gh);
            gA0 += PITCH; gA1 += PITCH; gA2 += PITCH; gA3 += PITCH;
            float4_t h0 = __builtin_amdgcn_mfma_f32_16x16x32_bf16(w1A[0], gu.s, cb1[0], 0, 0, 0);
            float4_t h1 = __builtin_amdgcn_mfma_f32_16x16x32_bf16(w1A[1], gu.s, cb1[1], 0, 0, 0);
            union { unsigned int u[4]; short8_t s; } hu;
            hu.u[0] = pk2t(fmaxf(h0[0],0.f), fmaxf(h0[1],0.f));
            hu.u[1] = pk2t(fmaxf(h0[2],0.f), fmaxf(h0[3],0.f));
            hu.u[2] = pk2t(fmaxf(h1[0],0.f), fmaxf(h1[1],0.f));
            hu.u[3] = pk2t(fmaxf(h1[2],0.f), fmaxf(h1[3],0.f));
            float4_t ka[4];
            #pragma unroll
            for (int nt = 0; nt < 4; ++nt)
                ka[nt] = __builtin_amdgcn_mfma_f32_16x16x32_bf16(w2A[nt], hu.s, cb2[nt], 0, 0, 0);
            float s = 0.f;
            #pragma unroll
            for (int i = 0; i < 15; ++i)
                s = fmaf(ka[i >> 2][i & 3], pvA[i], s);
            if (mt < 7) {
                #pragma unroll
                for (int i = 0; i < 10; ++i) pvA[i] = pvA[i + 5];
                pbA += PITCH;
                #pragma unroll
                for (int i = 10; i < 15; ++i) pvA[i] = smf[pbA + (i/5)*PITCH + (i%5)];
            }
            sA = s;
        }
        // ---------- stream B ----------
        float sB;
        {
            float ga = smf[gB0 + 0],  gb_ = smf[gB0 + 1];
            float gc = smf[gB1 + 2],  gd  = smf[gB1 + 23];
            float ge = smf[gB2 + 24], gf  = smf[gB2 + 25];
            float gg = smf[gB3 + 46], gh  = smf[gB3 + 47];
            union { unsigned int u[4]; short8_t s; } gu;
            gu.u[0] = pk2t(ga, gb_); gu.u[1] = pk2t(gc, gd);
            gu.u[2] = pk2t(ge, gf);  gu.u[3] = pk2t(gg, gh);
            gB0 += PITCH; gB1 += PITCH; gB2 += PITCH; gB3 += PITCH;
            float4_t h0 = __builtin_amdgcn_mfma_f32_16x16x32_bf16(w1A[0], gu.s, cb1[0], 0, 0, 0);
            float4_t h1 = __builtin_amdgcn_mfma_f32_16x16x32_bf16(w1A[1], gu.s, cb1[1], 0, 0, 0);
            union { unsigned int u[4]; short8_t s; } hu;
            hu.u[0] = pk2t(fmaxf(h0[0],0.f), fmaxf(h0[1],0.f));
            hu.u[1] = pk2t(fmaxf(h0[2],0.f), fmaxf(h0[3],0.f));
            hu.u[2] = pk2t(fmaxf(h1[0],0.f), fmaxf(h1[1],0.f));
            hu.u[3] = pk2t(fmaxf(h1[2],0.f), fmaxf(h1[3],0.f));
            float4_t ka[4];
            #pragma unroll
            for (int nt = 0; nt < 4; ++nt)
                ka[nt] = __builtin_amdgcn_mfma_f32_16x16x32_bf16(w2A[nt], hu.s, cb2[nt], 0, 0, 0);
            float s = 0.f;
            #pragma unroll
            for (int i = 0; i < 15; ++i)
                s = fmaf(ka[i >> 2][i & 3], pvB[i], s);
            if (mt < 7) {
                #pragma unroll
                for (int i = 0; i < 10; ++i) pvB[i] = pvB[i + 5];
                pbB += PITCH;
                #pragma unroll
                for (int i = 10; i < 15; ++i) pvB[i] = smf[pbB + (i/5)*PITCH + (i%5)];
            }
            sB = s;
        }

        // combine sel partitions: lanes g4 0<->1 (c=0), 2<->3 (c=1)
        sA += __shfl_xor(sA, 16);
        sB += __shfl_xor(sB, 16);

        if (sel == 0) {
            int x = x0 + col;
            size_t base = ((size_t)(b*2 + pc) * H) * W + x;
            out[base + (size_t)(y0 + tyA + mt) * W] = sA;
            out[base + (size_t)(y0 + tyB + mt) * W] = sB;
        }
    }
}

extern "C" void kernel_launch(void* const* d_in, const int* in_sizes, int n_in,
                              void* d_out, int out_size, void* d_ws, size_t ws_size,
                              hipStream_t stream) {
    const float* flow = (const float*)d_in[0];
    const float* w1   = (const float*)d_in[1];
    const float* b1   = (const float*)d_in[2];
    const float* w2   = (const float*)d_in[3];
    const float* b2   = (const float*)d_in[4];
    float* out = (float*)d_out;

    unsigned short* wp = (unsigned short*)d_ws;                 // 6*64*8 ushort = 6 KB
    float* bp = (float*)((char*)d_ws + 8192);                   // 6*64*4 float = 6 KB

    const int H = 1024, W = 1024;
    const int B = in_sizes[0] / (2 * H * W);

    pack_kernel<<<1, 256, 0, stream>>>(w1, b1, w2, b2, wp, bp);
    dim3 grid(W / TSX, H / TSY, B);
    refine_kernel<<<grid, dim3(256), 0, stream>>>(flow, wp, bp, out, H, W);
}

// Round 11
// 109.838 us; speedup vs baseline: 1.3115x; 1.3115x over previous
//
#include <hip/hip_runtime.h>
#include <math.h>

#define KSZ 5
#define TSX 16                // tile width (MFMA N = 16 pixels)
#define TSY 64                // tile height (each wave: 16 rows)
#define HALO 3
#define FWX 22                // staged cols = TSX + 6
#define FH  70                // staged rows = TSY + 6
#define SCH 66                // sc rows = TSY + 2
#define PITCH 23              // uniform pitch for sf planes AND sc plane
#define SF_C (FH*PITCH)       // 1610 floats per flow channel
#define SC_BASE (2*SF_C)
#define SMF_TOT (SC_BASE + SCH*PITCH)

typedef __attribute__((ext_vector_type(8))) short short8_t;  // 8 bf16
typedef __attribute__((ext_vector_type(4))) float float4_t;
typedef __attribute__((ext_vector_type(2))) unsigned int uint2_t;

static __device__ __forceinline__ unsigned short f2bf(float f) {
    union { float f; unsigned int u; } v; v.f = f;
    return (unsigned short)((v.u + 0x7FFFu + ((v.u >> 16) & 1u)) >> 16);  // RNE
}
// truncating bf16 pack: low16 = hi16(a), high16 = hi16(b) — ONE v_perm_b32
static __device__ __forceinline__ unsigned int pk2t(float a, float b) {
    union { float f; unsigned int u; } ua, ub; ua.f = a; ub.f = b;
    return __builtin_amdgcn_perm(ub.u, ua.u, 0x07060302u);
}
static __device__ __forceinline__ float bflo(unsigned int u) {
    union { unsigned int u; float f; } v; v.u = u << 16; return v.f;
}
static __device__ __forceinline__ float bfhi(unsigned int u) {
    union { unsigned int u; float f; } v; v.u = u & 0xffff0000u; return v.f;
}

// GEMM2 output slot n -> (c, sel, idx); j = sel*15 + idx; valid: sel?idx<10:idx<15
static __device__ __forceinline__ void slot_decode(int n, int& c, int& sel, int& idx, bool& valid) {
    int g4c = (n >> 2) & 3;
    c = g4c >> 1; sel = g4c & 1;
    idx = ((n >> 4) << 2) + (n & 3);
    valid = sel ? (idx < 10) : (idx < 15);
}

// GEMM1 K-permutation: k-slot s -> original guidance k (c*9 + ky*3 + kx), -1 = zero
static __device__ __forceinline__ int kperm(int s) {
    int sg = s >> 3, sj = s & 7;
    if (sg < 3) return sg*9 + sj;     // plane sg, taps 0..7
    if (sj == 1) return 8;            // c0 tap 8
    if (sj == 2) return 17;           // c1 tap 8
    if (sj == 4) return 26;           // cons tap 8
    return -1;
}

// GEMM2 K-permutation: k-slot s -> h channel the owning lane already holds.
static __device__ __forceinline__ int kperm2(int s) {
    int g = s >> 3, j = s & 7;
    return (j < 4) ? (g*4 + j) : (16 + g*4 + (j - 4));
}

// ---- one-block pack kernel: weights/biases -> MFMA-fragment order in ws ----
__global__ __launch_bounds__(256)
void pack_kernel(const float* __restrict__ w1, const float* __restrict__ b1,
                 const float* __restrict__ w2, const float* __restrict__ b2,
                 unsigned short* __restrict__ wp, float* __restrict__ bp)
{
    const int tid = threadIdx.x;
    for (int i = tid; i < 6*64*8; i += 256) {
        int f = i >> 9, l = (i >> 3) & 63, j = i & 7;
        int m = l & 15, s = ((l >> 4) << 3) + j;
        float v;
        if (f < 2) {
            int k = kperm(s);
            v = (k >= 0) ? w1[(f*16 + m)*27 + k] : 0.f;
        } else {
            int n = (f - 2)*16 + m;
            int c, sel, idx; bool valid;
            slot_decode(n, c, sel, idx, valid);
            v = valid ? w2[(c*25 + sel*15 + idx)*32 + kperm2(s)] : 0.f;
        }
        wp[i] = f2bf(v);
    }
    for (int i = tid; i < 6*64*4; i += 256) {
        int f = i >> 8, l = (i >> 2) & 63, r = i & 3, g4 = l >> 4;
        float v;
        if (f < 2) v = b1[f*16 + g4*4 + r];
        else {
            int n = (f - 2)*16 + g4*4 + r;
            int c, sel, idx; bool valid;
            slot_decode(n, c, sel, idx, valid);
            v = valid ? b2[c*25 + sel*15 + idx] : 0.f;
        }
        bp[i] = v;
    }
}

__global__ __launch_bounds__(256, 5)   // LDS 29184 -> 5 blocks/CU; single stream fits 96 VGPR
void refine_kernel(const float* __restrict__ flow,
                   const unsigned short* __restrict__ wp,
                   const float* __restrict__ bp,
                   float* __restrict__ out, int H, int W)
{
    __shared__ float smf[SMF_TOT];                 // sf[2][70][23] | sc[66][23]
    __shared__ __align__(8) uint2_t rs[FH*18];     // bf16-packed {sA|qA, sB|qB}

    const int tid = threadIdx.x;
    const int x0 = blockIdx.x * TSX;
    const int y0 = blockIdx.y * TSY;
    const int b  = blockIdx.z;

    const int lane = tid & 63;
    const int wave = tid >> 6;
    const int col  = lane & 15;
    const int g4   = lane >> 4;

    // ---- fragment loads from pre-packed ws ----
    short8_t w1A[2], w2A[4];
    float4_t cb1[2], cb2[4];
    #pragma unroll
    for (int nt = 0; nt < 2; ++nt) {
        w1A[nt] = *(const short8_t*)&wp[(nt*64 + lane)*8];
        cb1[nt] = *(const float4_t*)&bp[(nt*64 + lane)*4];
    }
    #pragma unroll
    for (int nt = 0; nt < 4; ++nt) {
        w2A[nt] = *(const short8_t*)&wp[((2+nt)*64 + lane)*8];
        cb2[nt] = *(const float4_t*)&bp[((2+nt)*64 + lane)*4];
    }

    // ---- phase 0: stage flow tile + halo ----
    {
        const float* srcb = flow + (size_t)(b*2) * H * W;
        if (x0 >= 4 && x0 + TSX + 4 <= W && y0 >= HALO && y0 + TSY + HALO <= H) {
            // interior: aligned float2 loads of 24 columns starting at x0-4
            const float* s = srcb + (size_t)(y0 - HALO) * W + (x0 - 4);
            for (int i = tid; i < 2*FH*12; i += 256) {
                int c = 0, r = i;
                if (r >= FH*12) { c = 1; r -= FH*12; }
                int ly = r / 12, lx2 = r - ly*12;
                float2 v = *(const float2*)(s + (size_t)c*H*W + (size_t)ly*W + 2*lx2);
                int dst = c*SF_C + ly*PITCH + 2*lx2 - 1;  // cols -1..22 -> -1 dropped
                if (dst >= 0) smf[dst] = v.x;
                smf[dst + 1] = v.y;
            }
        } else {
            for (int i = tid; i < 2*FH*FWX; i += 256) {
                int c = 0, r = i;
                if (r >= FH*FWX) { c = 1; r -= FH*FWX; }
                int ly = r / FWX, lx = r - ly*FWX;
                int gy = y0 - HALO + ly, gx = x0 - HALO + lx;
                float v = 0.f;
                if (gy >= 0 && gy < H && gx >= 0 && gx < W)
                    v = srcb[(size_t)c*H*W + (size_t)gy*W + gx];
                smf[c*SF_C + ly*PITCH + lx] = v;
            }
        }
    }
    __syncthreads();

    // ---- phase 1a: horizontal 5-tap sums (s, sum v^2), 2 adjacent outputs ----
    for (int i = tid; i < FH*9; i += 256) {        // 630 units
        int y = i / 9, xp = (i - y*9) * 2;
        const float* r0 = &smf[y*PITCH + xp];
        const float* r1 = &smf[SF_C + y*PITCH + xp];
        float a0=r0[0], a1=r0[1], a2=r0[2], a3=r0[3], a4=r0[4], a5=r0[5];
        float c0=r1[0], c1=r1[1], c2=r1[2], c3=r1[3], c4=r1[4], c5=r1[5];
        float sA = ((a0+a1)+(a2+a3))+a4;
        float qA = fmaf(a4,a4, fmaf(a3,a3, fmaf(a2,a2, fmaf(a1,a1, a0*a0))));
        float sB = ((c0+c1)+(c2+c3))+c4;
        float qB = fmaf(c4,c4, fmaf(c3,c3, fmaf(c2,c2, fmaf(c1,c1, c0*c0))));
        float sA1 = sA + a5 - a0;
        float qA1 = fmaf(-a0, a0, fmaf(a5, a5, qA));
        float sB1 = sB + c5 - c0;
        float qB1 = fmaf(-c0, c0, fmaf(c5, c5, qB));
        rs[y*18 + xp]     = (uint2_t){pk2t(sA,  qA ), pk2t(sB,  qB )};
        rs[y*18 + xp + 1] = (uint2_t){pk2t(sA1, qA1), pk2t(sB1, qB1)};
    }
    __syncthreads();

    // ---- phase 1b: vertical 5-row sums, 2 vertically-adjacent outputs/thread ----
    for (int i = tid; i < (SCH/2)*18; i += 256) {  // 594 units
        int u = i / 18, px = i - u*18;
        int py0 = u*2;
        int gx = x0 - 1 + px;
        int gy0 = y0 - 1 + py0;
        const uint2_t* rp = rs + py0*18 + px;
        float4_t f[6];
        #pragma unroll
        for (int k = 0; k < 6; ++k) {
            uint2_t uu = rp[k*18];
            f[k] = (float4_t){bflo(uu.x), bfhi(uu.x), bflo(uu.y), bfhi(uu.y)};
        }
        float4_t mid  = (f[1] + f[2]) + (f[3] + f[4]);
        float4_t acc0 = mid + f[0];
        float4_t acc1 = mid + f[5];
        float cons0 = 0.f, cons1 = 0.f;
        bool okx = (gx >= 0) && (gx < W);
        if (okx && gy0 >= 0 && gy0 < H) {
            float v0 = (acc0.y - acc0.x*acc0.x*(1.f/25.f)) * (1.f/24.f);
            float v1 = (acc0.w - acc0.z*acc0.z*(1.f/25.f)) * (1.f/24.f);
            cons0 = __expf(-sqrtf(v0*v0 + v1*v1));
        }
        if (okx && gy0+1 >= 0 && gy0+1 < H) {
            float v0 = (acc1.y - acc1.x*acc1.x*(1.f/25.f)) * (1.f/24.f);
            float v1 = (acc1.w - acc1.z*acc1.z*(1.f/25.f)) * (1.f/24.f);
            cons1 = __expf(-sqrtf(v0*v0 + v1*v1));
        }
        smf[SC_BASE + py0*PITCH + px]       = cons0;
        smf[SC_BASE + (py0+1)*PITCH + px]   = cons1;
    }
    __syncthreads();

    // ---- main: single row-stream per wave, 16 rows ----
    const int sel = g4 & 1, pc = g4 >> 1;
    const int ty0 = wave*16;

    // guidance bases (uniform immediates {0,1},{2,23},{24,25},{46,47})
    int gb0, gb1, gb2, gb3;
    {
        int p0 = 0*SF_C + 2*PITCH + (col + 2);
        int p1 = 1*SF_C + 2*PITCH + (col + 2);
        int p2 = SC_BASE + col;
        if (g4 == 0)      { gb0 = gb1 = gb2 = gb3 = p0; }
        else if (g4 == 1) { gb0 = gb1 = gb2 = gb3 = p1; }
        else if (g4 == 2) { gb0 = gb1 = gb2 = gb3 = p2; }
        else { gb0 = p0 + 47; gb1 = p1 + 46; gb2 = p2 + 24; gb3 = p0; }
        gb0 += ty0*PITCH; gb1 += ty0*PITCH; gb2 += ty0*PITCH; gb3 += ty0*PITCH;
    }

    // patch pipeline (15 taps; idx15 dropped — its ka is 0)
    int pb = pc*SF_C + sel*(3*PITCH) + PITCH + 1 + col + ty0*PITCH;
    float pv[15];
    #pragma unroll
    for (int i = 0; i < 15; ++i) pv[i] = smf[pb + (i/5)*PITCH + (i%5)];

    #pragma unroll
    for (int mt = 0; mt < 16; ++mt) {
        // guidance B-frag: 4 ds_read2_b32 (uniform immediates) + 4 perm packs
        float ga = smf[gb0 + 0],  gb_ = smf[gb0 + 1];
        float gc = smf[gb1 + 2],  gd  = smf[gb1 + 23];
        float ge = smf[gb2 + 24], gf  = smf[gb2 + 25];
        float gg = smf[gb3 + 46], gh  = smf[gb3 + 47];
        union { unsigned int u[4]; short8_t s; } gu;
        gu.u[0] = pk2t(ga, gb_); gu.u[1] = pk2t(gc, gd);
        gu.u[2] = pk2t(ge, gf);  gu.u[3] = pk2t(gg, gh);
        gb0 += PITCH; gb1 += PITCH; gb2 += PITCH; gb3 += PITCH;

        // GEMM1: h = relu(W1' . g + b1)
        float4_t h0 = __builtin_amdgcn_mfma_f32_16x16x32_bf16(w1A[0], gu.s, cb1[0], 0, 0, 0);
        float4_t h1 = __builtin_amdgcn_mfma_f32_16x16x32_bf16(w1A[1], gu.s, cb1[1], 0, 0, 0);

        // h B-frag built IN REGISTERS (kperm2 matches W2' K-order)
        union { unsigned int u[4]; short8_t s; } hu;
        hu.u[0] = pk2t(fmaxf(h0[0],0.f), fmaxf(h0[1],0.f));
        hu.u[1] = pk2t(fmaxf(h0[2],0.f), fmaxf(h0[3],0.f));
        hu.u[2] = pk2t(fmaxf(h1[0],0.f), fmaxf(h1[1],0.f));
        hu.u[3] = pk2t(fmaxf(h1[2],0.f), fmaxf(h1[3],0.f));

        // GEMM2: ka = W2' . h + b2'
        float4_t ka[4];
        #pragma unroll
        for (int nt = 0; nt < 4; ++nt)
            ka[nt] = __builtin_amdgcn_mfma_f32_16x16x32_bf16(w2A[nt], hu.s, cb2[nt], 0, 0, 0);

        // patch dot from the register pipeline
        float s = 0.f;
        #pragma unroll
        for (int i = 0; i < 15; ++i)
            s = fmaf(ka[i >> 2][i & 3], pv[i], s);

        if (mt < 15) {  // advance pipeline: tap(i,mt+1) = tap(i+5,mt)
            #pragma unroll
            for (int i = 0; i < 10; ++i) pv[i] = pv[i + 5];
            pb += PITCH;
            #pragma unroll
            for (int i = 10; i < 15; ++i) pv[i] = smf[pb + (i/5)*PITCH + (i%5)];
        }

        // combine sel partitions: lanes g4 0<->1 (c=0), 2<->3 (c=1)
        s += __shfl_xor(s, 16);

        if (sel == 0) {
            int y = y0 + ty0 + mt, x = x0 + col;
            out[((size_t)(b*2 + pc) * H + y) * W + x] = s;
        }
    }
}

extern "C" void kernel_launch(void* const* d_in, const int* in_sizes, int n_in,
                              void* d_out, int out_size, void* d_ws, size_t ws_size,
                              hipStream_t stream) {
    const float* flow = (const float*)d_in[0];
    const float* w1   = (const float*)d_in[1];
    const float* b1   = (const float*)d_in[2];
    const float* w2   = (const float*)d_in[3];
    const float* b2   = (const float*)d_in[4];
    float* out = (float*)d_out;

    unsigned short* wp = (unsigned short*)d_ws;                 // 6*64*8 ushort = 6 KB
    float* bp = (float*)((char*)d_ws + 8192);                   // 6*64*4 float = 6 KB

    const int H = 1024, W = 1024;
    const int B = in_sizes[0] / (2 * H * W);

    pack_kernel<<<1, 256, 0, stream>>>(w1, b1, w2, b2, wp, bp);
    dim3 grid(W / TSX, H / TSY, B);
    refine_kernel<<<grid, dim3(256), 0, stream>>>(flow, wp, bp, out, H, W);
}